// Round 2
// baseline (708.485 us; speedup 1.0000x reference)
//
#include <hip/hip_runtime.h>

#define D_DIM 128
#define P_TAB 4096   // v-table positions; >> max segment length (~330 for B=4096, N=1e6)

// batch is sorted; first element of each run writes its index (unique writer, no atomics).
__global__ void seg_first_kernel(const int* __restrict__ batch, int* __restrict__ seg_first, int N) {
    int i = blockIdx.x * blockDim.x + threadIdx.x;
    if (i < N) {
        int b = batch[i];
        if (i == 0 || batch[i - 1] != b) seg_first[b] = i;
    }
}

// Per position p: u = R(p)^T W2^T (rope folded into readout), v[p] = W1^T u, s[p] = u.b1 + b2.
// One block per p, 128 threads; W1 (64 KB) is L2-resident across all 4096 blocks.
__global__ __launch_bounds__(128)
void vtab_kernel(const float* __restrict__ W1, const float* __restrict__ b1,
                 const float* __restrict__ W2, const float* __restrict__ b2,
                 float* __restrict__ vtab, float* __restrict__ stab) {
    const int p = blockIdx.x;
    const int k = threadIdx.x;
    __shared__ float u[D_DIM];
    __shared__ float sred[D_DIM];
    if (k < 64) {
        // theta_j = 10000^(-j/64); accurate sinf/cosf (off critical path)
        float theta = exp2f(-(float)k * (13.287712379549449f / 64.0f));
        float ang = (float)p * theta;
        float c = cosf(ang), s = sinf(ang);
        float w0 = W2[2 * k], w1 = W2[2 * k + 1];
        // out = W2.R(p).h  =>  u[2j] = W2[2j]c + W2[2j+1]s ; u[2j+1] = W2[2j+1]c - W2[2j]s
        u[2 * k]     = w0 * c + w1 * s;
        u[2 * k + 1] = w1 * c - w0 * s;
    }
    __syncthreads();
    float acc = 0.f;
    #pragma unroll 8
    for (int d = 0; d < D_DIM; ++d)
        acc += u[d] * W1[d * D_DIM + k];     // coalesced across k; u broadcast from LDS
    vtab[p * D_DIM + k] = acc;
    sred[k] = u[k] * b1[k];
    __syncthreads();
    if (k == 0) {
        float s = b2[0];
        #pragma unroll 8
        for (int d = 0; d < D_DIM; ++d) s += sred[d];
        stab[p] = s;
    }
}

// out[n] = v(pos_n) . x_n + s(pos_n). Half-wave (32 lanes x float4) per row:
// a full wave covers 2 adjacent rows = 1 KB contiguous HBM per load instr.
__global__ __launch_bounds__(256)
void dot_kernel(const float* __restrict__ x, const int* __restrict__ batch,
                const int* __restrict__ seg_first,
                const float* __restrict__ vtab, const float* __restrict__ stab,
                float* __restrict__ out, int N) {
    const int lane = threadIdx.x & 63;
    const int half = lane >> 5;
    const int c    = lane & 31;
    const int gw   = (blockIdx.x * blockDim.x + threadIdx.x) >> 6;
    const int nw   = (gridDim.x * blockDim.x) >> 6;
    const int lastid = batch[N - 1];
    const int npairs = (N + 1) >> 1;

    for (int rp = gw; rp < npairs; rp += nw) {
        const int row = rp * 2 + half;
        float part = 0.f, sval = 0.f;
        const bool valid = (row < N);
        if (valid) {
            int b = batch[row];                      // same addr across half-wave: broadcast
            int pos = (b == lastid) ? 0 : (row - seg_first[b]);  // pos=0 <=> identity rope
            pos = (pos < P_TAB) ? pos : (P_TAB - 1); // clamp (never hit for this data)
            const float4 xv = *(const float4*)(x + (size_t)row * D_DIM + c * 4);
            const float4 vv = *(const float4*)(vtab + pos * D_DIM + c * 4);   // L2-resident
            part = xv.x * vv.x + xv.y * vv.y + xv.z * vv.z + xv.w * vv.w;
            sval = stab[pos];
        }
        // reduce across the 32 lanes of this half-wave (xor<32 stays within the half)
        part += __shfl_xor(part, 1, 64);
        part += __shfl_xor(part, 2, 64);
        part += __shfl_xor(part, 4, 64);
        part += __shfl_xor(part, 8, 64);
        part += __shfl_xor(part, 16, 64);
        if (valid && c == 0) out[row] = part + sval;
    }
}

extern "C" void kernel_launch(void* const* d_in, const int* in_sizes, int n_in,
                              void* d_out, int out_size, void* d_ws, size_t ws_size,
                              hipStream_t stream) {
    const float* x     = (const float*)d_in[0];
    const int*   batch = (const int*)d_in[1];
    const float* W1    = (const float*)d_in[2];
    const float* b1    = (const float*)d_in[3];
    const float* W2    = (const float*)d_in[4];
    const float* b2    = (const float*)d_in[5];
    float* out = (float*)d_out;
    const int N = in_sizes[1];

    // ws layout: seg_first (4096 int) | stab (P_TAB float) | vtab (P_TAB*128 float)
    int*   seg_first = (int*)d_ws;
    float* stab      = (float*)((char*)d_ws + 4096 * sizeof(int));
    float* vtab      = (float*)((char*)d_ws + 4096 * sizeof(int) + P_TAB * sizeof(float));

    seg_first_kernel<<<(N + 255) / 256, 256, 0, stream>>>(batch, seg_first, N);
    vtab_kernel<<<P_TAB, 128, 0, stream>>>(W1, b1, W2, b2, vtab, stab);

    // 2048 blocks x 256 thr = 8192 waves; tiny VGPR/no LDS -> full 32 waves/CU occupancy
    dot_kernel<<<2048, 256, 0, stream>>>(x, batch, seg_first, vtab, stab, out, N);
}